// Round 1
// baseline (409.231 us; speedup 1.0000x reference)
//
#include <hip/hip_runtime.h>

#define NTOK 4096
#define DDIM 1024
#define IDIM 704
#define NEXP 16
#define NSLOT 8192
#define MAXT 128

typedef __attribute__((ext_vector_type(8))) short bf16x8;
typedef __attribute__((ext_vector_type(4))) float f32x4;
typedef __attribute__((ext_vector_type(4))) unsigned short us4;

__device__ __forceinline__ unsigned short f2bf(float f) {
  union { float f; unsigned int u; } v; v.f = f;
  unsigned int r = v.u + 0x7fffu + ((v.u >> 16) & 1u);
  return (unsigned short)(r >> 16);
}

__device__ __forceinline__ void gload_lds16(const void* g, void* l) {
  __builtin_amdgcn_global_load_lds((const __attribute__((address_space(1))) void*)g,
                                   (__attribute__((address_space(3))) void*)l, 16, 0, 0);
}

// ---------------- x fp32 -> bf16 ----------------
__global__ void k_convert(const float* __restrict__ x, unsigned short* __restrict__ Xb) {
  int i = blockIdx.x * 256 + threadIdx.x;
  f32x4 v = ((const f32x4*)x)[i];
  us4 o;
#pragma unroll
  for (int j = 0; j < 4; ++j) o[j] = f2bf(v[j]);
  ((us4*)Xb)[i] = o;
}

// ---------------- router: wave per token, fp32 ----------------
__global__ void k_router(const float* __restrict__ x, const float* __restrict__ Wg,
                         int* __restrict__ tok_e, float* __restrict__ tok_w,
                         int* __restrict__ counts) {
  int lane = threadIdx.x & 63;
  int wv = threadIdx.x >> 6;
  int t = blockIdx.x * 4 + wv;
  const f32x4* xr = (const f32x4*)(x + (size_t)t * DDIM);
  f32x4 xv[4];
#pragma unroll
  for (int c = 0; c < 4; ++c) xv[c] = xr[c * 64 + lane];
  float p[NEXP];
#pragma unroll
  for (int e = 0; e < NEXP; ++e) {
    const f32x4* wr = (const f32x4*)(Wg + (size_t)e * DDIM);
    float s = 0.f;
#pragma unroll
    for (int c = 0; c < 4; ++c) {
      f32x4 w4 = wr[c * 64 + lane];
      s += xv[c][0]*w4[0] + xv[c][1]*w4[1] + xv[c][2]*w4[2] + xv[c][3]*w4[3];
    }
    p[e] = s;
  }
#pragma unroll
  for (int off = 32; off >= 1; off >>= 1) {
#pragma unroll
    for (int e = 0; e < NEXP; ++e) p[e] += __shfl_xor(p[e], off);
  }
  int i0 = 0; float b0 = p[0];
#pragma unroll
  for (int e = 1; e < NEXP; ++e) if (p[e] > b0) { b0 = p[e]; i0 = e; }
  int i1 = -1; float b1 = -3.4e38f;
#pragma unroll
  for (int e = 0; e < NEXP; ++e) if (e != i0 && p[e] > b1) { b1 = p[e]; i1 = e; }
  if (lane == 0) {
    float w0 = 1.f / (1.f + __expf(b1 - b0));   // renormalized top-2 softmax weight
    tok_e[2*t] = i0; tok_e[2*t+1] = i1;
    tok_w[2*t] = w0; tok_w[2*t+1] = 1.f - w0;
    atomicAdd(&counts[i0], 1); atomicAdd(&counts[i1], 1);
  }
}

// ---------------- scan: offsets + tile list ----------------
__global__ void k_scan(const int* __restrict__ counts, int* __restrict__ offsets,
                       int* __restrict__ cursors, int* __restrict__ ntiles,
                       int* __restrict__ tile_e, int* __restrict__ tile_m0) {
  if (threadIdx.x == 0) {
    int acc = 0, nt = 0;
    for (int e = 0; e < NEXP; ++e) {
      offsets[e] = acc;
      int c = counts[e];
      for (int m0 = 0; m0 < c; m0 += 128) { tile_e[nt] = e; tile_m0[nt] = m0; ++nt; }
      acc += c;
      cursors[e] = 0;
    }
    offsets[NEXP] = acc;
    *ntiles = nt;
  }
}

// ---------------- scatter: token-pairs -> grouped slots ----------------
__global__ void k_scatter(const int* __restrict__ tok_e, const float* __restrict__ tok_w,
                          const int* __restrict__ offsets, int* __restrict__ cursors,
                          int* __restrict__ token_map, float* __restrict__ gate_w,
                          int* __restrict__ slot_of) {
  int i = blockIdx.x * 256 + threadIdx.x;   // 0..8191
  int e = tok_e[i];
  int pos = atomicAdd(&cursors[e], 1);
  int slot = offsets[e] + pos;
  token_map[slot] = i >> 1;
  gate_w[slot] = tok_w[i];
  slot_of[i] = slot;
}

// ---------------- GEMM1: H = gate * silu(X@W1) * (X@W3), grouped ----------------
__global__ __launch_bounds__(256, 2)
void k_gemm1(const unsigned short* __restrict__ Xb, const float* __restrict__ W1,
             const float* __restrict__ W3, const int* __restrict__ token_map,
             const float* __restrict__ gate_w, const int* __restrict__ ntiles,
             const int* __restrict__ tile_e, const int* __restrict__ tile_m0,
             const int* __restrict__ offsets, const int* __restrict__ counts,
             unsigned short* __restrict__ H) {
  int ty = blockIdx.y;
  if (ty >= *ntiles) return;
  int e = tile_e[ty], m0 = tile_m0[ty];
  int n0 = blockIdx.x * 128;
  int base_slot = offsets[e] + m0;
  int cnt = counts[e] - m0; if (cnt > 128) cnt = 128;

  __shared__ unsigned short As[128 * 32];
  __shared__ unsigned short B1s[128 * 32];
  __shared__ unsigned short B3s[128 * 32];

  int t = threadIdx.x;
  // A staging: global_load_lds 16B, swizzle folded into source k-group
  int src_kg = (t & 3) ^ ((t >> 4) & 3);
  int r0i = base_slot + (t >> 2);        if (r0i > NSLOT - 1) r0i = NSLOT - 1;
  int r1i = base_slot + 64 + (t >> 2);   if (r1i > NSLOT - 1) r1i = NSLOT - 1;
  const unsigned short* ag0 = Xb + (size_t)token_map[r0i] * DDIM + src_kg * 8;
  const unsigned short* ag1 = Xb + (size_t)token_map[r1i] * DDIM + src_kg * 8;
  unsigned short* asd0 = As + t * 8;
  unsigned short* asd1 = As + 2048 + t * 8;

  // B staging: 4x4 register transpose, fp32->bf16, [n][k] LDS, XOR swizzle
  int nb = t & 31, kb = t >> 5;
  int nloc = nb * 4, kloc = kb * 4;
  int gn = n0 + nloc;
  bool nvalid = gn < IDIM;
  const float* w1p = W1 + (size_t)e * DDIM * IDIM + (size_t)kloc * IDIM + gn;
  const float* w3p = W3 + (size_t)e * DDIM * IDIM + (size_t)kloc * IDIM + gn;
  int wo[4];
#pragma unroll
  for (int j = 0; j < 4; ++j) {
    int row = nloc + j;
    wo[j] = row * 32 + ((((kb >> 1) ^ (row >> 2)) & 3) << 3) + ((kb & 1) << 2);
  }

  int lane = t & 63, wv = t >> 6;
  int wm = (wv >> 1) * 64, wn = (wv & 1) * 64;
  int lm = lane & 15, kg = lane >> 4;
  int ao[4], bo[4];
#pragma unroll
  for (int i = 0; i < 4; ++i) {
    int m = wm + i * 16 + lm;
    ao[i] = m * 32 + (((kg ^ (m >> 2)) & 3) << 3);
    int n = wn + i * 16 + lm;
    bo[i] = n * 32 + (((kg ^ (n >> 2)) & 3) << 3);
  }

  f32x4 acc1[4][4], acc3[4][4];
#pragma unroll
  for (int i = 0; i < 4; ++i)
#pragma unroll
    for (int j = 0; j < 4; ++j) { acc1[i][j] = 0.f; acc3[i][j] = 0.f; }

  for (int k0 = 0; k0 < DDIM; k0 += 32) {
    f32x4 fa[4], fb[4];
#pragma unroll
    for (int j = 0; j < 4; ++j) {
      if (nvalid) {
        fa[j] = *(const f32x4*)(w1p + (size_t)(k0 + j) * IDIM);
        fb[j] = *(const f32x4*)(w3p + (size_t)(k0 + j) * IDIM);
      } else { fa[j] = 0.f; fb[j] = 0.f; }
    }
    __syncthreads();
    gload_lds16(ag0 + k0, asd0);
    gload_lds16(ag1 + k0, asd1);
#pragma unroll
    for (int j = 0; j < 4; ++j) {
      us4 o1, o3;
#pragma unroll
      for (int jj = 0; jj < 4; ++jj) { o1[jj] = f2bf(fa[jj][j]); o3[jj] = f2bf(fb[jj][j]); }
      *(us4*)(B1s + wo[j]) = o1;
      *(us4*)(B3s + wo[j]) = o3;
    }
    __syncthreads();
    bf16x8 av[4], b1v[4], b3v[4];
#pragma unroll
    for (int i = 0; i < 4; ++i) {
      av[i]  = *(const bf16x8*)(As + ao[i]);
      b1v[i] = *(const bf16x8*)(B1s + bo[i]);
      b3v[i] = *(const bf16x8*)(B3s + bo[i]);
    }
#pragma unroll
    for (int mi = 0; mi < 4; ++mi)
#pragma unroll
      for (int ni = 0; ni < 4; ++ni) {
        acc1[mi][ni] = __builtin_amdgcn_mfma_f32_16x16x32_bf16(av[mi], b1v[ni], acc1[mi][ni], 0, 0, 0);
        acc3[mi][ni] = __builtin_amdgcn_mfma_f32_16x16x32_bf16(av[mi], b3v[ni], acc3[mi][ni], 0, 0, 0);
      }
  }

  // epilogue: SwiGLU * gate -> bf16 H
#pragma unroll
  for (int mi = 0; mi < 4; ++mi)
#pragma unroll
    for (int r = 0; r < 4; ++r) {
      int row = wm + mi * 16 + kg * 4 + r;
      if (row < cnt) {
        int slot = base_slot + row;
        float gw = gate_w[slot];
        unsigned short* hrow = H + (size_t)slot * IDIM;
#pragma unroll
        for (int ni = 0; ni < 4; ++ni) {
          int nn = n0 + wn + ni * 16 + lm;
          if (nn < IDIM) {
            float v1 = acc1[mi][ni][r];
            float v3 = acc3[mi][ni][r];
            float h = v1 / (1.f + __expf(-v1)) * v3 * gw;
            hrow[nn] = f2bf(h);
          }
        }
      }
    }
}

// ---------------- GEMM2: O2 = H @ W2, grouped ----------------
__global__ __launch_bounds__(256, 2)
void k_gemm2(const unsigned short* __restrict__ H, const float* __restrict__ W2,
             const int* __restrict__ ntiles, const int* __restrict__ tile_e,
             const int* __restrict__ tile_m0, const int* __restrict__ offsets,
             const int* __restrict__ counts, float* __restrict__ O2) {
  int ty = blockIdx.y;
  if (ty >= *ntiles) return;
  int e = tile_e[ty], m0 = tile_m0[ty];
  int n0 = blockIdx.x * 128;
  int base_slot = offsets[e] + m0;
  int cnt = counts[e] - m0; if (cnt > 128) cnt = 128;

  __shared__ unsigned short As[128 * 32];
  __shared__ unsigned short Bs[128 * 32];

  int t = threadIdx.x;
  int src_kg = (t & 3) ^ ((t >> 4) & 3);
  int r0i = base_slot + (t >> 2);        if (r0i > NSLOT - 1) r0i = NSLOT - 1;
  int r1i = base_slot + 64 + (t >> 2);   if (r1i > NSLOT - 1) r1i = NSLOT - 1;
  const unsigned short* ag0 = H + (size_t)r0i * IDIM + src_kg * 8;
  const unsigned short* ag1 = H + (size_t)r1i * IDIM + src_kg * 8;
  unsigned short* asd0 = As + t * 8;
  unsigned short* asd1 = As + 2048 + t * 8;

  int nb = t & 31, kb = t >> 5;
  int nloc = nb * 4, kloc = kb * 4;
  int gn = n0 + nloc;
  const float* w2p = W2 + (size_t)e * IDIM * DDIM + (size_t)kloc * DDIM + gn;
  int wo[4];
#pragma unroll
  for (int j = 0; j < 4; ++j) {
    int row = nloc + j;
    wo[j] = row * 32 + ((((kb >> 1) ^ (row >> 2)) & 3) << 3) + ((kb & 1) << 2);
  }

  int lane = t & 63, wv = t >> 6;
  int wm = (wv >> 1) * 64, wn = (wv & 1) * 64;
  int lm = lane & 15, kg = lane >> 4;
  int ao[4], bo[4];
#pragma unroll
  for (int i = 0; i < 4; ++i) {
    int m = wm + i * 16 + lm;
    ao[i] = m * 32 + (((kg ^ (m >> 2)) & 3) << 3);
    int n = wn + i * 16 + lm;
    bo[i] = n * 32 + (((kg ^ (n >> 2)) & 3) << 3);
  }

  f32x4 acc[4][4];
#pragma unroll
  for (int i = 0; i < 4; ++i)
#pragma unroll
    for (int j = 0; j < 4; ++j) acc[i][j] = 0.f;

  for (int k0 = 0; k0 < IDIM; k0 += 32) {
    f32x4 fw[4];
#pragma unroll
    for (int j = 0; j < 4; ++j)
      fw[j] = *(const f32x4*)(w2p + (size_t)(k0 + j) * DDIM);
    __syncthreads();
    gload_lds16(ag0 + k0, asd0);
    gload_lds16(ag1 + k0, asd1);
#pragma unroll
    for (int j = 0; j < 4; ++j) {
      us4 o;
#pragma unroll
      for (int jj = 0; jj < 4; ++jj) o[jj] = f2bf(fw[jj][j]);
      *(us4*)(Bs + wo[j]) = o;
    }
    __syncthreads();
    bf16x8 av[4], bv[4];
#pragma unroll
    for (int i = 0; i < 4; ++i) {
      av[i] = *(const bf16x8*)(As + ao[i]);
      bv[i] = *(const bf16x8*)(Bs + bo[i]);
    }
#pragma unroll
    for (int mi = 0; mi < 4; ++mi)
#pragma unroll
      for (int ni = 0; ni < 4; ++ni)
        acc[mi][ni] = __builtin_amdgcn_mfma_f32_16x16x32_bf16(av[mi], bv[ni], acc[mi][ni], 0, 0, 0);
  }

#pragma unroll
  for (int mi = 0; mi < 4; ++mi)
#pragma unroll
    for (int r = 0; r < 4; ++r) {
      int row = wm + mi * 16 + kg * 4 + r;
      if (row < cnt) {
        float* orow = O2 + (size_t)(base_slot + row) * DDIM + n0;
#pragma unroll
        for (int ni = 0; ni < 4; ++ni)
          orow[wn + ni * 16 + lm] = acc[mi][ni][r];
      }
    }
}

// ---------------- combine: out[t] = O2[slot0] + O2[slot1] ----------------
__global__ void k_combine(const float* __restrict__ O2, const int* __restrict__ slot_of,
                          float* __restrict__ out) {
  int tk = blockIdx.x, tt = threadIdx.x;
  int s0 = slot_of[2 * tk], s1 = slot_of[2 * tk + 1];
  f32x4 a = ((const f32x4*)(O2 + (size_t)s0 * DDIM))[tt];
  f32x4 b = ((const f32x4*)(O2 + (size_t)s1 * DDIM))[tt];
  ((f32x4*)(out + (size_t)tk * DDIM))[tt] = a + b;
}

extern "C" void kernel_launch(void* const* d_in, const int* in_sizes, int n_in,
                              void* d_out, int out_size, void* d_ws, size_t ws_size,
                              hipStream_t stream) {
  const float* x  = (const float*)d_in[0];
  const float* Wg = (const float*)d_in[1];
  const float* W1 = (const float*)d_in[2];
  const float* W2 = (const float*)d_in[3];   // dict order: x, Wg, W1, W2, W3
  const float* W3 = (const float*)d_in[4];
  float* out = (float*)d_out;

  char* ws = (char*)d_ws;
  size_t off = 0;
  unsigned short* Xb = (unsigned short*)(ws + off); off += (size_t)NTOK * DDIM * 2;
  unsigned short* H  = (unsigned short*)(ws + off); off += (size_t)NSLOT * IDIM * 2;
  float* O2 = (float*)(ws + off); off += (size_t)NSLOT * DDIM * 4;
  int* counts  = (int*)(ws + off); off += 64;
  int* cursors = (int*)(ws + off); off += 64;
  int* offsets = (int*)(ws + off); off += 128;
  int* ntiles  = (int*)(ws + off); off += 64;
  int* tile_e  = (int*)(ws + off); off += MAXT * 4;
  int* tile_m0 = (int*)(ws + off); off += MAXT * 4;
  int* tok_e   = (int*)(ws + off); off += NSLOT * 4;
  float* tok_w = (float*)(ws + off); off += NSLOT * 4;
  int* token_map = (int*)(ws + off); off += NSLOT * 4;
  float* gate_w  = (float*)(ws + off); off += NSLOT * 4;
  int* slot_of   = (int*)(ws + off); off += NSLOT * 4;

  hipMemsetAsync(counts, 0, 64, stream);
  k_convert<<<4096, 256, 0, stream>>>(x, Xb);
  k_router<<<1024, 256, 0, stream>>>(x, Wg, tok_e, tok_w, counts);
  k_scan<<<1, 64, 0, stream>>>(counts, offsets, cursors, ntiles, tile_e, tile_m0);
  k_scatter<<<32, 256, 0, stream>>>(tok_e, tok_w, offsets, cursors, token_map, gate_w, slot_of);
  k_gemm1<<<dim3(6, 80), 256, 0, stream>>>(Xb, W1, W3, token_map, gate_w, ntiles, tile_e,
                                           tile_m0, offsets, counts, H);
  k_gemm2<<<dim3(8, 80), 256, 0, stream>>>(H, W2, ntiles, tile_e, tile_m0, offsets, counts, O2);
  k_combine<<<4096, 256, 0, stream>>>(O2, slot_of, out);
}

// Round 2
// 321.483 us; speedup vs baseline: 1.2729x; 1.2729x over previous
//
#include <hip/hip_runtime.h>

#define NTOK 4096
#define DDIM 1024
#define IDIM 704
#define NEXP 16
#define NSLOT 8192
#define MAXT 128

typedef __attribute__((ext_vector_type(8))) short bf16x8;
typedef __attribute__((ext_vector_type(4))) float f32x4;
typedef __attribute__((ext_vector_type(4))) unsigned short us4;

__device__ __forceinline__ unsigned short f2bf(float f) {
  union { float f; unsigned int u; } v; v.f = f;
  unsigned int r = v.u + 0x7fffu + ((v.u >> 16) & 1u);
  return (unsigned short)(r >> 16);
}

__device__ __forceinline__ void gload_lds16(const void* g, void* l) {
  __builtin_amdgcn_global_load_lds((const __attribute__((address_space(1))) void*)g,
                                   (__attribute__((address_space(3))) void*)l, 16, 0, 0);
}

// ---------------- x fp32 -> bf16 ----------------
__global__ void k_convert(const float* __restrict__ x, unsigned short* __restrict__ Xb) {
  int i = blockIdx.x * 256 + threadIdx.x;
  f32x4 v = ((const f32x4*)x)[i];
  us4 o;
#pragma unroll
  for (int j = 0; j < 4; ++j) o[j] = f2bf(v[j]);
  ((us4*)Xb)[i] = o;
}

// ---------------- router: wave per token, fp32, NO atomics ----------------
__global__ void k_router(const float* __restrict__ x, const float* __restrict__ Wg,
                         int* __restrict__ tok_e, float* __restrict__ tok_w) {
  int lane = threadIdx.x & 63;
  int wv = threadIdx.x >> 6;
  int t = blockIdx.x * 4 + wv;
  const f32x4* xr = (const f32x4*)(x + (size_t)t * DDIM);
  f32x4 xv[4];
#pragma unroll
  for (int c = 0; c < 4; ++c) xv[c] = xr[c * 64 + lane];
  float p[NEXP];
#pragma unroll
  for (int e = 0; e < NEXP; ++e) {
    const f32x4* wr = (const f32x4*)(Wg + (size_t)e * DDIM);
    float s = 0.f;
#pragma unroll
    for (int c = 0; c < 4; ++c) {
      f32x4 w4 = wr[c * 64 + lane];
      s += xv[c][0]*w4[0] + xv[c][1]*w4[1] + xv[c][2]*w4[2] + xv[c][3]*w4[3];
    }
    p[e] = s;
  }
#pragma unroll
  for (int off = 32; off >= 1; off >>= 1) {
#pragma unroll
    for (int e = 0; e < NEXP; ++e) p[e] += __shfl_xor(p[e], off);
  }
  int i0 = 0; float b0 = p[0];
#pragma unroll
  for (int e = 1; e < NEXP; ++e) if (p[e] > b0) { b0 = p[e]; i0 = e; }
  int i1 = -1; float b1 = -3.4e38f;
#pragma unroll
  for (int e = 0; e < NEXP; ++e) if (e != i0 && p[e] > b1) { b1 = p[e]; i1 = e; }
  if (lane == 0) {
    float w0 = 1.f / (1.f + __expf(b1 - b0));   // renormalized top-2 softmax weight
    tok_e[2*t] = i0; tok_e[2*t+1] = i1;
    tok_w[2*t] = w0; tok_w[2*t+1] = 1.f - w0;
  }
}

// ---------------- count + scan: single block, no atomics ----------------
__global__ void k_count_scan(const int* __restrict__ tok_e, int* __restrict__ counts,
                             int* __restrict__ offsets, int* __restrict__ ntiles,
                             int* __restrict__ tile_e, int* __restrict__ tile_m0) {
  __shared__ int h[256 * 17];
  __shared__ int counts_s[NEXP];
  int t = threadIdx.x;
  int c[NEXP];
#pragma unroll
  for (int e = 0; e < NEXP; ++e) c[e] = 0;
  for (int i = t; i < NSLOT; i += 256) {
    int te = tok_e[i];
#pragma unroll
    for (int e = 0; e < NEXP; ++e) c[e] += (te == e) ? 1 : 0;
  }
#pragma unroll
  for (int e = 0; e < NEXP; ++e) h[t * 17 + e] = c[e];
  __syncthreads();
  if (t < NEXP) {
    int s = 0;
    for (int i = 0; i < 256; ++i) s += h[i * 17 + t];
    counts_s[t] = s;
    counts[t] = s;
  }
  __syncthreads();
  if (t == 0) {
    int acc = 0, nt = 0;
    for (int e = 0; e < NEXP; ++e) {
      offsets[e] = acc;
      int cc = counts_s[e];
      for (int m0 = 0; m0 < cc; m0 += 128) { tile_e[nt] = e; tile_m0[nt] = m0; ++nt; }
      acc += cc;
    }
    offsets[NEXP] = acc;
    *ntiles = nt;
  }
}

// ---------------- scatter: one block per expert, deterministic, no atomics ----------------
__global__ void k_scatter2(const int* __restrict__ tok_e, const float* __restrict__ tok_w,
                           const int* __restrict__ offsets, int* __restrict__ token_map,
                           float* __restrict__ gate_w, int* __restrict__ slot_of) {
  int e = blockIdx.x;
  int t = threadIdx.x, lane = t & 63, wv = t >> 6;
  int te[32]; float tw[32];
#pragma unroll
  for (int c = 0; c < 32; ++c) {
    te[c] = tok_e[c * 256 + t];
    tw[c] = tok_w[c * 256 + t];
  }
  __shared__ int wsum[4];
  int run = offsets[e];
  unsigned long long below = (lane == 63) ? 0x7fffffffffffffffull : ((1ull << lane) - 1ull);
#pragma unroll 1
  for (int c = 0; c < 32; ++c) {
    bool f = (te[c] == e);
    unsigned long long m = __ballot(f);
    if (lane == 0) wsum[wv] = __popcll(m);
    __syncthreads();
    int base = run;
    for (int w = 0; w < wv; ++w) base += wsum[w];
    int tot = wsum[0] + wsum[1] + wsum[2] + wsum[3];
    if (f) {
      int i = c * 256 + t;
      int slot = base + __popcll(m & below);
      token_map[slot] = i >> 1;
      gate_w[slot] = tw[c];
      slot_of[i] = slot;
    }
    run += tot;
    __syncthreads();
  }
}

// ---------------- GEMM1: H = gate * silu(X@W1) * (X@W3), grouped ----------------
__global__ __launch_bounds__(256, 2)
void k_gemm1(const unsigned short* __restrict__ Xb, const float* __restrict__ W1,
             const float* __restrict__ W3, const int* __restrict__ token_map,
             const float* __restrict__ gate_w, const int* __restrict__ ntiles,
             const int* __restrict__ tile_e, const int* __restrict__ tile_m0,
             const int* __restrict__ offsets, const int* __restrict__ counts,
             unsigned short* __restrict__ H) {
  int ty = blockIdx.y;
  if (ty >= *ntiles) return;
  int e = tile_e[ty], m0 = tile_m0[ty];
  int n0 = blockIdx.x * 128;
  int base_slot = offsets[e] + m0;
  int cnt = counts[e] - m0; if (cnt > 128) cnt = 128;

  __shared__ unsigned short As[128 * 32];
  __shared__ unsigned short B1s[128 * 32];
  __shared__ unsigned short B3s[128 * 32];

  int t = threadIdx.x;
  // A staging: global_load_lds 16B, swizzle folded into source k-group
  int src_kg = (t & 3) ^ ((t >> 4) & 3);
  int r0i = base_slot + (t >> 2);        if (r0i > NSLOT - 1) r0i = NSLOT - 1;
  int r1i = base_slot + 64 + (t >> 2);   if (r1i > NSLOT - 1) r1i = NSLOT - 1;
  const unsigned short* ag0 = Xb + (size_t)token_map[r0i] * DDIM + src_kg * 8;
  const unsigned short* ag1 = Xb + (size_t)token_map[r1i] * DDIM + src_kg * 8;
  unsigned short* asd0 = As + t * 8;
  unsigned short* asd1 = As + 2048 + t * 8;

  // B staging: 4x4 register transpose, fp32->bf16, [n][k] LDS, XOR swizzle
  int nb = t & 31, kb = t >> 5;
  int nloc = nb * 4, kloc = kb * 4;
  int gn = n0 + nloc;
  bool nvalid = gn < IDIM;
  const float* w1p = W1 + (size_t)e * DDIM * IDIM + (size_t)kloc * IDIM + gn;
  const float* w3p = W3 + (size_t)e * DDIM * IDIM + (size_t)kloc * IDIM + gn;
  int wo[4];
#pragma unroll
  for (int j = 0; j < 4; ++j) {
    int row = nloc + j;
    wo[j] = row * 32 + ((((kb >> 1) ^ (row >> 2)) & 3) << 3) + ((kb & 1) << 2);
  }

  int lane = t & 63, wv = t >> 6;
  int wm = (wv >> 1) * 64, wn = (wv & 1) * 64;
  int lm = lane & 15, kg = lane >> 4;
  int ao[4], bo[4];
#pragma unroll
  for (int i = 0; i < 4; ++i) {
    int m = wm + i * 16 + lm;
    ao[i] = m * 32 + (((kg ^ (m >> 2)) & 3) << 3);
    int n = wn + i * 16 + lm;
    bo[i] = n * 32 + (((kg ^ (n >> 2)) & 3) << 3);
  }

  f32x4 acc1[4][4], acc3[4][4];
#pragma unroll
  for (int i = 0; i < 4; ++i)
#pragma unroll
    for (int j = 0; j < 4; ++j) { acc1[i][j] = 0.f; acc3[i][j] = 0.f; }

  for (int k0 = 0; k0 < DDIM; k0 += 32) {
    f32x4 fa[4], fb[4];
#pragma unroll
    for (int j = 0; j < 4; ++j) {
      if (nvalid) {
        fa[j] = *(const f32x4*)(w1p + (size_t)(k0 + j) * IDIM);
        fb[j] = *(const f32x4*)(w3p + (size_t)(k0 + j) * IDIM);
      } else { fa[j] = 0.f; fb[j] = 0.f; }
    }
    __syncthreads();
    gload_lds16(ag0 + k0, asd0);
    gload_lds16(ag1 + k0, asd1);
#pragma unroll
    for (int j = 0; j < 4; ++j) {
      us4 o1, o3;
#pragma unroll
      for (int jj = 0; jj < 4; ++jj) { o1[jj] = f2bf(fa[jj][j]); o3[jj] = f2bf(fb[jj][j]); }
      *(us4*)(B1s + wo[j]) = o1;
      *(us4*)(B3s + wo[j]) = o3;
    }
    __syncthreads();
    bf16x8 av[4], b1v[4], b3v[4];
#pragma unroll
    for (int i = 0; i < 4; ++i) {
      av[i]  = *(const bf16x8*)(As + ao[i]);
      b1v[i] = *(const bf16x8*)(B1s + bo[i]);
      b3v[i] = *(const bf16x8*)(B3s + bo[i]);
    }
#pragma unroll
    for (int mi = 0; mi < 4; ++mi)
#pragma unroll
      for (int ni = 0; ni < 4; ++ni) {
        acc1[mi][ni] = __builtin_amdgcn_mfma_f32_16x16x32_bf16(av[mi], b1v[ni], acc1[mi][ni], 0, 0, 0);
        acc3[mi][ni] = __builtin_amdgcn_mfma_f32_16x16x32_bf16(av[mi], b3v[ni], acc3[mi][ni], 0, 0, 0);
      }
  }

  // epilogue: SwiGLU * gate -> bf16 H
#pragma unroll
  for (int mi = 0; mi < 4; ++mi)
#pragma unroll
    for (int r = 0; r < 4; ++r) {
      int row = wm + mi * 16 + kg * 4 + r;
      if (row < cnt) {
        int slot = base_slot + row;
        float gw = gate_w[slot];
        unsigned short* hrow = H + (size_t)slot * IDIM;
#pragma unroll
        for (int ni = 0; ni < 4; ++ni) {
          int nn = n0 + wn + ni * 16 + lm;
          if (nn < IDIM) {
            float v1 = acc1[mi][ni][r];
            float v3 = acc3[mi][ni][r];
            float h = v1 / (1.f + __expf(-v1)) * v3 * gw;
            hrow[nn] = f2bf(h);
          }
        }
      }
    }
}

// ---------------- GEMM2: O2 = H @ W2, grouped ----------------
__global__ __launch_bounds__(256, 2)
void k_gemm2(const unsigned short* __restrict__ H, const float* __restrict__ W2,
             const int* __restrict__ ntiles, const int* __restrict__ tile_e,
             const int* __restrict__ tile_m0, const int* __restrict__ offsets,
             const int* __restrict__ counts, float* __restrict__ O2) {
  int ty = blockIdx.y;
  if (ty >= *ntiles) return;
  int e = tile_e[ty], m0 = tile_m0[ty];
  int n0 = blockIdx.x * 128;
  int base_slot = offsets[e] + m0;
  int cnt = counts[e] - m0; if (cnt > 128) cnt = 128;

  __shared__ unsigned short As[128 * 32];
  __shared__ unsigned short Bs[128 * 32];

  int t = threadIdx.x;
  int src_kg = (t & 3) ^ ((t >> 4) & 3);
  int r0i = base_slot + (t >> 2);        if (r0i > NSLOT - 1) r0i = NSLOT - 1;
  int r1i = base_slot + 64 + (t >> 2);   if (r1i > NSLOT - 1) r1i = NSLOT - 1;
  const unsigned short* ag0 = H + (size_t)r0i * IDIM + src_kg * 8;
  const unsigned short* ag1 = H + (size_t)r1i * IDIM + src_kg * 8;
  unsigned short* asd0 = As + t * 8;
  unsigned short* asd1 = As + 2048 + t * 8;

  int nb = t & 31, kb = t >> 5;
  int nloc = nb * 4, kloc = kb * 4;
  int gn = n0 + nloc;
  const float* w2p = W2 + (size_t)e * IDIM * DDIM + (size_t)kloc * DDIM + gn;
  int wo[4];
#pragma unroll
  for (int j = 0; j < 4; ++j) {
    int row = nloc + j;
    wo[j] = row * 32 + ((((kb >> 1) ^ (row >> 2)) & 3) << 3) + ((kb & 1) << 2);
  }

  int lane = t & 63, wv = t >> 6;
  int wm = (wv >> 1) * 64, wn = (wv & 1) * 64;
  int lm = lane & 15, kg = lane >> 4;
  int ao[4], bo[4];
#pragma unroll
  for (int i = 0; i < 4; ++i) {
    int m = wm + i * 16 + lm;
    ao[i] = m * 32 + (((kg ^ (m >> 2)) & 3) << 3);
    int n = wn + i * 16 + lm;
    bo[i] = n * 32 + (((kg ^ (n >> 2)) & 3) << 3);
  }

  f32x4 acc[4][4];
#pragma unroll
  for (int i = 0; i < 4; ++i)
#pragma unroll
    for (int j = 0; j < 4; ++j) acc[i][j] = 0.f;

  for (int k0 = 0; k0 < IDIM; k0 += 32) {
    f32x4 fw[4];
#pragma unroll
    for (int j = 0; j < 4; ++j)
      fw[j] = *(const f32x4*)(w2p + (size_t)(k0 + j) * DDIM);
    __syncthreads();
    gload_lds16(ag0 + k0, asd0);
    gload_lds16(ag1 + k0, asd1);
#pragma unroll
    for (int j = 0; j < 4; ++j) {
      us4 o;
#pragma unroll
      for (int jj = 0; jj < 4; ++jj) o[jj] = f2bf(fw[jj][j]);
      *(us4*)(Bs + wo[j]) = o;
    }
    __syncthreads();
    bf16x8 av[4], bv[4];
#pragma unroll
    for (int i = 0; i < 4; ++i) {
      av[i] = *(const bf16x8*)(As + ao[i]);
      bv[i] = *(const bf16x8*)(Bs + bo[i]);
    }
#pragma unroll
    for (int mi = 0; mi < 4; ++mi)
#pragma unroll
      for (int ni = 0; ni < 4; ++ni)
        acc[mi][ni] = __builtin_amdgcn_mfma_f32_16x16x32_bf16(av[mi], bv[ni], acc[mi][ni], 0, 0, 0);
  }

#pragma unroll
  for (int mi = 0; mi < 4; ++mi)
#pragma unroll
    for (int r = 0; r < 4; ++r) {
      int row = wm + mi * 16 + kg * 4 + r;
      if (row < cnt) {
        float* orow = O2 + (size_t)(base_slot + row) * DDIM + n0;
#pragma unroll
        for (int ni = 0; ni < 4; ++ni)
          orow[wn + ni * 16 + lm] = acc[mi][ni][r];
      }
    }
}

// ---------------- combine: out[t] = O2[slot0] + O2[slot1] ----------------
__global__ void k_combine(const float* __restrict__ O2, const int* __restrict__ slot_of,
                          float* __restrict__ out) {
  int tk = blockIdx.x, tt = threadIdx.x;
  int s0 = slot_of[2 * tk], s1 = slot_of[2 * tk + 1];
  f32x4 a = ((const f32x4*)(O2 + (size_t)s0 * DDIM))[tt];
  f32x4 b = ((const f32x4*)(O2 + (size_t)s1 * DDIM))[tt];
  ((f32x4*)(out + (size_t)tk * DDIM))[tt] = a + b;
}

extern "C" void kernel_launch(void* const* d_in, const int* in_sizes, int n_in,
                              void* d_out, int out_size, void* d_ws, size_t ws_size,
                              hipStream_t stream) {
  const float* x  = (const float*)d_in[0];
  const float* Wg = (const float*)d_in[1];
  const float* W1 = (const float*)d_in[2];
  const float* W2 = (const float*)d_in[3];   // dict order: x, Wg, W1, W2, W3
  const float* W3 = (const float*)d_in[4];
  float* out = (float*)d_out;

  char* ws = (char*)d_ws;
  size_t off = 0;
  unsigned short* Xb = (unsigned short*)(ws + off); off += (size_t)NTOK * DDIM * 2;
  unsigned short* H  = (unsigned short*)(ws + off); off += (size_t)NSLOT * IDIM * 2;
  float* O2 = (float*)(ws + off); off += (size_t)NSLOT * DDIM * 4;
  int* counts  = (int*)(ws + off); off += 64;
  int* offsets = (int*)(ws + off); off += 128;
  int* ntiles  = (int*)(ws + off); off += 64;
  int* tile_e  = (int*)(ws + off); off += MAXT * 4;
  int* tile_m0 = (int*)(ws + off); off += MAXT * 4;
  int* tok_e   = (int*)(ws + off); off += NSLOT * 4;
  float* tok_w = (float*)(ws + off); off += NSLOT * 4;
  int* token_map = (int*)(ws + off); off += NSLOT * 4;
  float* gate_w  = (float*)(ws + off); off += NSLOT * 4;
  int* slot_of   = (int*)(ws + off); off += NSLOT * 4;

  k_convert<<<4096, 256, 0, stream>>>(x, Xb);
  k_router<<<1024, 256, 0, stream>>>(x, Wg, tok_e, tok_w);
  k_count_scan<<<1, 256, 0, stream>>>(tok_e, counts, offsets, ntiles, tile_e, tile_m0);
  k_scatter2<<<NEXP, 256, 0, stream>>>(tok_e, tok_w, offsets, token_map, gate_w, slot_of);
  k_gemm1<<<dim3(6, 80), 256, 0, stream>>>(Xb, W1, W3, token_map, gate_w, ntiles, tile_e,
                                           tile_m0, offsets, counts, H);
  k_gemm2<<<dim3(8, 80), 256, 0, stream>>>(H, W2, ntiles, tile_e, tile_m0, offsets, counts, O2);
  k_combine<<<4096, 256, 0, stream>>>(O2, slot_of, out);
}

// Round 3
// 317.681 us; speedup vs baseline: 1.2882x; 1.0120x over previous
//
#include <hip/hip_runtime.h>

#define NTOK 4096
#define DDIM 1024
#define IDIM 704
#define NEXP 16
#define NSLOT 8192
#define MAXT 128
#define NPAD1 768   // IDIM padded to 128 multiple for gemm1 n-dim

typedef __attribute__((ext_vector_type(8))) short bf16x8;
typedef __attribute__((ext_vector_type(4))) float f32x4;
typedef __attribute__((ext_vector_type(4))) unsigned short us4;
typedef __attribute__((ext_vector_type(8))) unsigned short us8;

__device__ __forceinline__ unsigned short f2bf(float f) {
  union { float f; unsigned int u; } v; v.f = f;
  unsigned int r = v.u + 0x7fffu + ((v.u >> 16) & 1u);
  return (unsigned short)(r >> 16);
}

__device__ __forceinline__ void gload_lds16(const void* g, void* l) {
  __builtin_amdgcn_global_load_lds((const __attribute__((address_space(1))) void*)g,
                                   (__attribute__((address_space(3))) void*)l, 16, 0, 0);
}

// ---------------- x fp32 -> bf16 ----------------
__global__ void k_convert(const float* __restrict__ x, unsigned short* __restrict__ Xb) {
  int i = blockIdx.x * 256 + threadIdx.x;
  f32x4 v = ((const f32x4*)x)[i];
  us4 o;
#pragma unroll
  for (int j = 0; j < 4; ++j) o[j] = f2bf(v[j]);
  ((us4*)Xb)[i] = o;
}

// ---------------- weight transpose+convert: [e][k][n] fp32 -> [e][npad][k] bf16 ----------------
// npad = gridDim.y*64. Tiles are always full (ksz,nsz multiples of 64); tiles with
// n0 >= nsz write zeros (n-padding rows).
__global__ void k_wtrans(const float* __restrict__ src, unsigned short* __restrict__ dst,
                         int ksz, int nsz) {
  int e = blockIdx.z;
  int k0 = blockIdx.x * 64, n0 = blockIdx.y * 64;
  int npad = gridDim.y * 64;
  src += (size_t)e * ksz * nsz;
  dst += (size_t)e * npad * ksz;
  int t = threadIdx.x;
  int nr = t >> 3, kc0 = (t & 7) * 8;
  if (n0 >= nsz) {
    us8 z = (us8)0;
#pragma unroll
    for (int p = 0; p < 2; ++p)
      *(us8*)(dst + (size_t)(n0 + nr + p * 32) * ksz + k0 + kc0) = z;
    return;
  }
  __shared__ unsigned short lds[64 * 76];
  int nc = (t & 15) * 4, kr = t >> 4;
#pragma unroll
  for (int p = 0; p < 4; ++p) {
    f32x4 v = *(const f32x4*)(src + (size_t)(k0 + kr + p * 16) * nsz + n0 + nc);
    us4 o;
#pragma unroll
    for (int j = 0; j < 4; ++j) o[j] = f2bf(v[j]);
    *(us4*)(lds + (kr + p * 16) * 76 + nc) = o;
  }
  __syncthreads();
#pragma unroll
  for (int p = 0; p < 2; ++p) {
    int row = nr + p * 32;
    us8 o;
#pragma unroll
    for (int j = 0; j < 8; ++j) o[j] = lds[(kc0 + j) * 76 + row];
    *(us8*)(dst + (size_t)(n0 + row) * ksz + k0 + kc0) = o;
  }
}

// ---------------- router: wave per token, fp32, NO atomics ----------------
__global__ void k_router(const float* __restrict__ x, const float* __restrict__ Wg,
                         int* __restrict__ tok_e, float* __restrict__ tok_w) {
  int lane = threadIdx.x & 63;
  int wv = threadIdx.x >> 6;
  int t = blockIdx.x * 4 + wv;
  const f32x4* xr = (const f32x4*)(x + (size_t)t * DDIM);
  f32x4 xv[4];
#pragma unroll
  for (int c = 0; c < 4; ++c) xv[c] = xr[c * 64 + lane];
  float p[NEXP];
#pragma unroll
  for (int e = 0; e < NEXP; ++e) {
    const f32x4* wr = (const f32x4*)(Wg + (size_t)e * DDIM);
    float s = 0.f;
#pragma unroll
    for (int c = 0; c < 4; ++c) {
      f32x4 w4 = wr[c * 64 + lane];
      s += xv[c][0]*w4[0] + xv[c][1]*w4[1] + xv[c][2]*w4[2] + xv[c][3]*w4[3];
    }
    p[e] = s;
  }
#pragma unroll
  for (int off = 32; off >= 1; off >>= 1) {
#pragma unroll
    for (int e = 0; e < NEXP; ++e) p[e] += __shfl_xor(p[e], off);
  }
  int i0 = 0; float b0 = p[0];
#pragma unroll
  for (int e = 1; e < NEXP; ++e) if (p[e] > b0) { b0 = p[e]; i0 = e; }
  int i1 = -1; float b1 = -3.4e38f;
#pragma unroll
  for (int e = 0; e < NEXP; ++e) if (e != i0 && p[e] > b1) { b1 = p[e]; i1 = e; }
  if (lane == 0) {
    float w0 = 1.f / (1.f + __expf(b1 - b0));   // renormalized top-2 softmax weight
    tok_e[2*t] = i0; tok_e[2*t+1] = i1;
    tok_w[2*t] = w0; tok_w[2*t+1] = 1.f - w0;
  }
}

// ---------------- count + scan: single block, no atomics ----------------
__global__ void k_count_scan(const int* __restrict__ tok_e, int* __restrict__ counts,
                             int* __restrict__ offsets, int* __restrict__ ntiles,
                             int* __restrict__ tile_e, int* __restrict__ tile_m0) {
  __shared__ int h[256 * 17];
  __shared__ int counts_s[NEXP];
  int t = threadIdx.x;
  int c[NEXP];
#pragma unroll
  for (int e = 0; e < NEXP; ++e) c[e] = 0;
  for (int i = t; i < NSLOT; i += 256) {
    int te = tok_e[i];
#pragma unroll
    for (int e = 0; e < NEXP; ++e) c[e] += (te == e) ? 1 : 0;
  }
#pragma unroll
  for (int e = 0; e < NEXP; ++e) h[t * 17 + e] = c[e];
  __syncthreads();
  if (t < NEXP) {
    int s = 0;
    for (int i = 0; i < 256; ++i) s += h[i * 17 + t];
    counts_s[t] = s;
    counts[t] = s;
  }
  __syncthreads();
  if (t == 0) {
    int acc = 0, nt = 0;
    for (int e = 0; e < NEXP; ++e) {
      offsets[e] = acc;
      int cc = counts_s[e];
      for (int m0 = 0; m0 < cc; m0 += 128) { tile_e[nt] = e; tile_m0[nt] = m0; ++nt; }
      acc += cc;
    }
    offsets[NEXP] = acc;
    *ntiles = nt;
  }
}

// ---------------- scatter: one block per expert, deterministic, no atomics ----------------
__global__ void k_scatter2(const int* __restrict__ tok_e, const float* __restrict__ tok_w,
                           const int* __restrict__ offsets, int* __restrict__ token_map,
                           float* __restrict__ gate_w, int* __restrict__ slot_of) {
  int e = blockIdx.x;
  int t = threadIdx.x, lane = t & 63, wv = t >> 6;
  int te[32]; float tw[32];
#pragma unroll
  for (int c = 0; c < 32; ++c) {
    te[c] = tok_e[c * 256 + t];
    tw[c] = tok_w[c * 256 + t];
  }
  __shared__ int wsum[4];
  int run = offsets[e];
  unsigned long long below = (lane == 63) ? 0x7fffffffffffffffull : ((1ull << lane) - 1ull);
#pragma unroll 1
  for (int c = 0; c < 32; ++c) {
    bool f = (te[c] == e);
    unsigned long long m = __ballot(f);
    if (lane == 0) wsum[wv] = __popcll(m);
    __syncthreads();
    int base = run;
    for (int w = 0; w < wv; ++w) base += wsum[w];
    int tot = wsum[0] + wsum[1] + wsum[2] + wsum[3];
    if (f) {
      int i = c * 256 + t;
      int slot = base + __popcll(m & below);
      token_map[slot] = i >> 1;
      gate_w[slot] = tw[c];
      slot_of[i] = slot;
    }
    run += tot;
    __syncthreads();
  }
}

// ---------------- GEMM1: H = gate * silu(X@W1) * (X@W3), grouped, all-async staging ----------------
__global__ __launch_bounds__(256, 2)
void k_gemm1(const unsigned short* __restrict__ Xb, const unsigned short* __restrict__ W1T,
             const unsigned short* __restrict__ W3T, const int* __restrict__ token_map,
             const float* __restrict__ gate_w, const int* __restrict__ ntiles,
             const int* __restrict__ tile_e, const int* __restrict__ tile_m0,
             const int* __restrict__ offsets, const int* __restrict__ counts,
             unsigned short* __restrict__ H) {
  int ty = blockIdx.y;
  if (ty >= *ntiles) return;
  int e = tile_e[ty], m0 = tile_m0[ty];
  int n0 = blockIdx.x * 128;
  int base_slot = offsets[e] + m0;
  int cnt = counts[e] - m0; if (cnt > 128) cnt = 128;

  __shared__ unsigned short As[128 * 32];
  __shared__ unsigned short B1s[128 * 32];
  __shared__ unsigned short B3s[128 * 32];

  int t = threadIdx.x;
  int row = t >> 2, kc = (t & 3) * 8;
  int r0i = base_slot + row;      if (r0i > NSLOT - 1) r0i = NSLOT - 1;
  int r1i = base_slot + 64 + row; if (r1i > NSLOT - 1) r1i = NSLOT - 1;
  const unsigned short* ag0 = Xb + (size_t)token_map[r0i] * DDIM + kc;
  const unsigned short* ag1 = Xb + (size_t)token_map[r1i] * DDIM + kc;
  const unsigned short* b1g0 = W1T + ((size_t)e * NPAD1 + n0 + row) * DDIM + kc;
  const unsigned short* b1g1 = b1g0 + (size_t)64 * DDIM;
  const unsigned short* b3g0 = W3T + ((size_t)e * NPAD1 + n0 + row) * DDIM + kc;
  const unsigned short* b3g1 = b3g0 + (size_t)64 * DDIM;
  unsigned short* asd0 = As + t * 8;   unsigned short* asd1 = As + 2048 + t * 8;
  unsigned short* b1d0 = B1s + t * 8;  unsigned short* b1d1 = B1s + 2048 + t * 8;
  unsigned short* b3d0 = B3s + t * 8;  unsigned short* b3d1 = B3s + 2048 + t * 8;

  int lane = t & 63, wv = t >> 6;
  int wm = (wv >> 1) * 64, wn = (wv & 1) * 64;
  int lm = lane & 15, kg = lane >> 4;
  int ao[4], bo[4];
#pragma unroll
  for (int i = 0; i < 4; ++i) {
    ao[i] = (wm + i * 16 + lm) * 32 + kg * 8;
    bo[i] = (wn + i * 16 + lm) * 32 + kg * 8;
  }

  f32x4 acc1[4][4], acc3[4][4];
#pragma unroll
  for (int i = 0; i < 4; ++i)
#pragma unroll
    for (int j = 0; j < 4; ++j) { acc1[i][j] = 0.f; acc3[i][j] = 0.f; }

  for (int k0 = 0; k0 < DDIM; k0 += 32) {
    __syncthreads();
    gload_lds16(ag0 + k0, asd0);
    gload_lds16(ag1 + k0, asd1);
    gload_lds16(b1g0 + k0, b1d0);
    gload_lds16(b1g1 + k0, b1d1);
    gload_lds16(b3g0 + k0, b3d0);
    gload_lds16(b3g1 + k0, b3d1);
    __syncthreads();
    bf16x8 av[4], b1v[4], b3v[4];
#pragma unroll
    for (int i = 0; i < 4; ++i) {
      av[i]  = *(const bf16x8*)(As + ao[i]);
      b1v[i] = *(const bf16x8*)(B1s + bo[i]);
      b3v[i] = *(const bf16x8*)(B3s + bo[i]);
    }
#pragma unroll
    for (int mi = 0; mi < 4; ++mi)
#pragma unroll
      for (int ni = 0; ni < 4; ++ni) {
        acc1[mi][ni] = __builtin_amdgcn_mfma_f32_16x16x32_bf16(av[mi], b1v[ni], acc1[mi][ni], 0, 0, 0);
        acc3[mi][ni] = __builtin_amdgcn_mfma_f32_16x16x32_bf16(av[mi], b3v[ni], acc3[mi][ni], 0, 0, 0);
      }
  }

  // epilogue: SwiGLU * gate -> bf16 H
#pragma unroll
  for (int mi = 0; mi < 4; ++mi)
#pragma unroll
    for (int r = 0; r < 4; ++r) {
      int orow = wm + mi * 16 + kg * 4 + r;
      if (orow < cnt) {
        int slot = base_slot + orow;
        float gw = gate_w[slot];
        unsigned short* hrow = H + (size_t)slot * IDIM;
#pragma unroll
        for (int ni = 0; ni < 4; ++ni) {
          int nn = n0 + wn + ni * 16 + lm;
          if (nn < IDIM) {
            float v1 = acc1[mi][ni][r];
            float v3 = acc3[mi][ni][r];
            float h = v1 / (1.f + __expf(-v1)) * v3 * gw;
            hrow[nn] = f2bf(h);
          }
        }
      }
    }
}

// ---------------- GEMM2: O2 = H @ W2, grouped, all-async staging ----------------
__global__ __launch_bounds__(256, 3)
void k_gemm2(const unsigned short* __restrict__ H, const unsigned short* __restrict__ W2T,
             const int* __restrict__ ntiles, const int* __restrict__ tile_e,
             const int* __restrict__ tile_m0, const int* __restrict__ offsets,
             const int* __restrict__ counts, float* __restrict__ O2) {
  int ty = blockIdx.y;
  if (ty >= *ntiles) return;
  int e = tile_e[ty], m0 = tile_m0[ty];
  int n0 = blockIdx.x * 128;
  int base_slot = offsets[e] + m0;
  int cnt = counts[e] - m0; if (cnt > 128) cnt = 128;

  __shared__ unsigned short As[128 * 32];
  __shared__ unsigned short Bs[128 * 32];

  int t = threadIdx.x;
  int row = t >> 2, kc = (t & 3) * 8;
  int r0i = base_slot + row;      if (r0i > NSLOT - 1) r0i = NSLOT - 1;
  int r1i = base_slot + 64 + row; if (r1i > NSLOT - 1) r1i = NSLOT - 1;
  const unsigned short* ag0 = H + (size_t)r0i * IDIM + kc;
  const unsigned short* ag1 = H + (size_t)r1i * IDIM + kc;
  const unsigned short* bg0 = W2T + ((size_t)e * DDIM + n0 + row) * IDIM + kc;
  const unsigned short* bg1 = bg0 + (size_t)64 * IDIM;
  unsigned short* asd0 = As + t * 8;  unsigned short* asd1 = As + 2048 + t * 8;
  unsigned short* bd0 = Bs + t * 8;   unsigned short* bd1 = Bs + 2048 + t * 8;

  int lane = t & 63, wv = t >> 6;
  int wm = (wv >> 1) * 64, wn = (wv & 1) * 64;
  int lm = lane & 15, kg = lane >> 4;
  int ao[4], bo[4];
#pragma unroll
  for (int i = 0; i < 4; ++i) {
    ao[i] = (wm + i * 16 + lm) * 32 + kg * 8;
    bo[i] = (wn + i * 16 + lm) * 32 + kg * 8;
  }

  f32x4 acc[4][4];
#pragma unroll
  for (int i = 0; i < 4; ++i)
#pragma unroll
    for (int j = 0; j < 4; ++j) acc[i][j] = 0.f;

  for (int k0 = 0; k0 < IDIM; k0 += 32) {
    __syncthreads();
    gload_lds16(ag0 + k0, asd0);
    gload_lds16(ag1 + k0, asd1);
    gload_lds16(bg0 + k0, bd0);
    gload_lds16(bg1 + k0, bd1);
    __syncthreads();
    bf16x8 av[4], bv[4];
#pragma unroll
    for (int i = 0; i < 4; ++i) {
      av[i] = *(const bf16x8*)(As + ao[i]);
      bv[i] = *(const bf16x8*)(Bs + bo[i]);
    }
#pragma unroll
    for (int mi = 0; mi < 4; ++mi)
#pragma unroll
      for (int ni = 0; ni < 4; ++ni)
        acc[mi][ni] = __builtin_amdgcn_mfma_f32_16x16x32_bf16(av[mi], bv[ni], acc[mi][ni], 0, 0, 0);
  }

#pragma unroll
  for (int mi = 0; mi < 4; ++mi)
#pragma unroll
    for (int r = 0; r < 4; ++r) {
      int orow = wm + mi * 16 + kg * 4 + r;
      if (orow < cnt) {
        float* op = O2 + (size_t)(base_slot + orow) * DDIM + n0;
#pragma unroll
        for (int ni = 0; ni < 4; ++ni)
          op[wn + ni * 16 + lm] = acc[mi][ni][r];
      }
    }
}

// ---------------- combine: out[t] = O2[slot0] + O2[slot1] ----------------
__global__ void k_combine(const float* __restrict__ O2, const int* __restrict__ slot_of,
                          float* __restrict__ out) {
  int tk = blockIdx.x, tt = threadIdx.x;
  int s0 = slot_of[2 * tk], s1 = slot_of[2 * tk + 1];
  f32x4 a = ((const f32x4*)(O2 + (size_t)s0 * DDIM))[tt];
  f32x4 b = ((const f32x4*)(O2 + (size_t)s1 * DDIM))[tt];
  ((f32x4*)(out + (size_t)tk * DDIM))[tt] = a + b;
}

extern "C" void kernel_launch(void* const* d_in, const int* in_sizes, int n_in,
                              void* d_out, int out_size, void* d_ws, size_t ws_size,
                              hipStream_t stream) {
  const float* x  = (const float*)d_in[0];
  const float* Wg = (const float*)d_in[1];
  const float* W1 = (const float*)d_in[2];
  const float* W2 = (const float*)d_in[3];   // dict order: x, Wg, W1, W2, W3
  const float* W3 = (const float*)d_in[4];
  float* out = (float*)d_out;

  char* ws = (char*)d_ws;
  size_t off = 0;
  unsigned short* Xb = (unsigned short*)(ws + off); off += (size_t)NTOK * DDIM * 2;
  unsigned short* H  = (unsigned short*)(ws + off); off += (size_t)NSLOT * IDIM * 2;
  float* O2 = (float*)(ws + off); off += (size_t)NSLOT * DDIM * 4;
  unsigned short* W1T = (unsigned short*)(ws + off); off += (size_t)NEXP * NPAD1 * DDIM * 2;
  unsigned short* W3T = (unsigned short*)(ws + off); off += (size_t)NEXP * NPAD1 * DDIM * 2;
  unsigned short* W2T = (unsigned short*)(ws + off); off += (size_t)NEXP * DDIM * IDIM * 2;
  int* counts  = (int*)(ws + off); off += 64;
  int* offsets = (int*)(ws + off); off += 128;
  int* ntiles  = (int*)(ws + off); off += 64;
  int* tile_e  = (int*)(ws + off); off += MAXT * 4;
  int* tile_m0 = (int*)(ws + off); off += MAXT * 4;
  int* tok_e   = (int*)(ws + off); off += NSLOT * 4;
  float* tok_w = (float*)(ws + off); off += NSLOT * 4;
  int* token_map = (int*)(ws + off); off += NSLOT * 4;
  float* gate_w  = (float*)(ws + off); off += NSLOT * 4;
  int* slot_of   = (int*)(ws + off); off += NSLOT * 4;

  k_convert<<<4096, 256, 0, stream>>>(x, Xb);
  k_router<<<1024, 256, 0, stream>>>(x, Wg, tok_e, tok_w);
  k_count_scan<<<1, 256, 0, stream>>>(tok_e, counts, offsets, ntiles, tile_e, tile_m0);
  k_scatter2<<<NEXP, 256, 0, stream>>>(tok_e, tok_w, offsets, token_map, gate_w, slot_of);
  k_wtrans<<<dim3(16, 12, NEXP), 256, 0, stream>>>(W1, W1T, DDIM, IDIM);
  k_wtrans<<<dim3(16, 12, NEXP), 256, 0, stream>>>(W3, W3T, DDIM, IDIM);
  k_wtrans<<<dim3(11, 16, NEXP), 256, 0, stream>>>(W2, W2T, IDIM, DDIM);
  k_gemm1<<<dim3(6, 80), 256, 0, stream>>>(Xb, W1T, W3T, token_map, gate_w, ntiles, tile_e,
                                           tile_m0, offsets, counts, H);
  k_gemm2<<<dim3(8, 80), 256, 0, stream>>>(H, W2T, ntiles, tile_e, tile_m0, offsets, counts, O2);
  k_combine<<<4096, 256, 0, stream>>>(O2, slot_of, out);
}

// Round 4
// 308.072 us; speedup vs baseline: 1.3284x; 1.0312x over previous
//
#include <hip/hip_runtime.h>

#define NTOK 4096
#define DDIM 1024
#define IDIM 704
#define NEXP 16
#define NSLOT 8192
#define MAXT 128
#define NPAD1 768   // IDIM padded to 128 multiple for gemm1 n-dim

typedef __attribute__((ext_vector_type(8))) short bf16x8;
typedef __attribute__((ext_vector_type(4))) float f32x4;
typedef __attribute__((ext_vector_type(4))) unsigned short us4;
typedef __attribute__((ext_vector_type(8))) unsigned short us8;

__device__ __forceinline__ unsigned short f2bf(float f) {
  union { float f; unsigned int u; } v; v.f = f;
  unsigned int r = v.u + 0x7fffu + ((v.u >> 16) & 1u);
  return (unsigned short)(r >> 16);
}

__device__ __forceinline__ void gload_lds16(const void* g, void* l) {
  __builtin_amdgcn_global_load_lds((const __attribute__((address_space(1))) void*)g,
                                   (__attribute__((address_space(3))) void*)l, 16, 0, 0);
}

// ---------------- router + x->bf16 convert, fused; NO atomics ----------------
__global__ void k_router(const float* __restrict__ x, const float* __restrict__ Wg,
                         int* __restrict__ tok_e, float* __restrict__ tok_w,
                         unsigned short* __restrict__ Xb) {
  int lane = threadIdx.x & 63;
  int wv = threadIdx.x >> 6;
  int t = blockIdx.x * 4 + wv;
  const f32x4* xr = (const f32x4*)(x + (size_t)t * DDIM);
  us4* xbr = (us4*)(Xb + (size_t)t * DDIM);
  f32x4 xv[4];
#pragma unroll
  for (int c = 0; c < 4; ++c) {
    xv[c] = xr[c * 64 + lane];
    us4 o;
#pragma unroll
    for (int j = 0; j < 4; ++j) o[j] = f2bf(xv[c][j]);
    xbr[c * 64 + lane] = o;
  }
  float p[NEXP];
#pragma unroll
  for (int e = 0; e < NEXP; ++e) {
    const f32x4* wr = (const f32x4*)(Wg + (size_t)e * DDIM);
    float s = 0.f;
#pragma unroll
    for (int c = 0; c < 4; ++c) {
      f32x4 w4 = wr[c * 64 + lane];
      s += xv[c][0]*w4[0] + xv[c][1]*w4[1] + xv[c][2]*w4[2] + xv[c][3]*w4[3];
    }
    p[e] = s;
  }
#pragma unroll
  for (int off = 32; off >= 1; off >>= 1) {
#pragma unroll
    for (int e = 0; e < NEXP; ++e) p[e] += __shfl_xor(p[e], off);
  }
  int i0 = 0; float b0 = p[0];
#pragma unroll
  for (int e = 1; e < NEXP; ++e) if (p[e] > b0) { b0 = p[e]; i0 = e; }
  int i1 = -1; float b1 = -3.4e38f;
#pragma unroll
  for (int e = 0; e < NEXP; ++e) if (e != i0 && p[e] > b1) { b1 = p[e]; i1 = e; }
  if (lane == 0) {
    float w0 = 1.f / (1.f + __expf(b1 - b0));   // renormalized top-2 softmax weight
    tok_e[2*t] = i0; tok_e[2*t+1] = i1;
    tok_w[2*t] = w0; tok_w[2*t+1] = 1.f - w0;
  }
}

// ---------------- weight transpose+convert: [e][k][n] fp32 -> [e][npad][k] bf16 ----------------
// 64x64 tiles, register 4x4 transpose -> XOR-swizzled LDS [n][k] -> b128 reads.
__global__ void k_wtrans(const float* __restrict__ src, unsigned short* __restrict__ dst,
                         int ksz, int nsz, int npad) {
  int e = blockIdx.z;
  int k0 = blockIdx.x * 64, n0 = blockIdx.y * 64;
  src += (size_t)e * ksz * nsz;
  dst += (size_t)e * npad * ksz;
  int t = threadIdx.x;
  if (n0 >= nsz) {            // n-padding rows: write zeros
    int nr = t >> 3, kc0 = (t & 7) * 8;
    us8 z = (us8)(unsigned short)0;
#pragma unroll
    for (int p = 0; p < 2; ++p)
      *(us8*)(dst + (size_t)(n0 + nr + p * 32) * ksz + k0 + kc0) = z;
    return;
  }
  __shared__ unsigned short lds[64 * 64];
  int kr4 = (t >> 4) * 4, nc4 = (t & 15) * 4;
  f32x4 v[4];
#pragma unroll
  for (int j = 0; j < 4; ++j)
    v[j] = *(const f32x4*)(src + (size_t)(k0 + kr4 + j) * nsz + n0 + nc4);
  int c8 = kr4 >> 3, half = (kr4 >> 2) & 1;
#pragma unroll
  for (int i = 0; i < 4; ++i) {
    us4 o;
#pragma unroll
    for (int j = 0; j < 4; ++j) o[j] = f2bf(v[j][i]);
    int row = nc4 + i;
    int addr = row * 64 + ((c8 ^ ((row >> 2) & 7)) << 3) + half * 4;
    *(us4*)(lds + addr) = o;
  }
  __syncthreads();
  int nr = t >> 3, kc8 = t & 7;
#pragma unroll
  for (int p = 0; p < 2; ++p) {
    int row = nr + p * 32;
    us8 o = *(const us8*)(lds + row * 64 + ((kc8 ^ ((row >> 2) & 7)) << 3));
    *(us8*)(dst + (size_t)(n0 + row) * ksz + k0 + kc8 * 8) = o;
  }
}

// ---------------- count + scan: single block, no atomics ----------------
__global__ void k_count_scan(const int* __restrict__ tok_e, int* __restrict__ counts,
                             int* __restrict__ offsets, int* __restrict__ ntiles,
                             int* __restrict__ tile_e, int* __restrict__ tile_m0) {
  __shared__ int h[256 * 17];
  __shared__ int counts_s[NEXP];
  int t = threadIdx.x;
  int c[NEXP];
#pragma unroll
  for (int e = 0; e < NEXP; ++e) c[e] = 0;
  for (int i = t; i < NSLOT; i += 256) {
    int te = tok_e[i];
#pragma unroll
    for (int e = 0; e < NEXP; ++e) c[e] += (te == e) ? 1 : 0;
  }
#pragma unroll
  for (int e = 0; e < NEXP; ++e) h[t * 17 + e] = c[e];
  __syncthreads();
  if (t < NEXP) {
    int s = 0;
    for (int i = 0; i < 256; ++i) s += h[i * 17 + t];
    counts_s[t] = s;
    counts[t] = s;
  }
  __syncthreads();
  if (t == 0) {
    int acc = 0, nt = 0;
    for (int e = 0; e < NEXP; ++e) {
      offsets[e] = acc;
      int cc = counts_s[e];
      for (int m0 = 0; m0 < cc; m0 += 128) { tile_e[nt] = e; tile_m0[nt] = m0; ++nt; }
      acc += cc;
    }
    offsets[NEXP] = acc;
    *ntiles = nt;
  }
}

// ---------------- scatter: one block per expert, deterministic, no atomics ----------------
__global__ void k_scatter2(const int* __restrict__ tok_e, const float* __restrict__ tok_w,
                           const int* __restrict__ offsets, int* __restrict__ token_map,
                           float* __restrict__ gate_w, int* __restrict__ slot_of) {
  int e = blockIdx.x;
  int t = threadIdx.x, lane = t & 63, wv = t >> 6;
  int te[32]; float tw[32];
#pragma unroll
  for (int c = 0; c < 32; ++c) {
    te[c] = tok_e[c * 256 + t];
    tw[c] = tok_w[c * 256 + t];
  }
  __shared__ int wsum[4];
  int run = offsets[e];
  unsigned long long below = (lane == 63) ? 0x7fffffffffffffffull : ((1ull << lane) - 1ull);
#pragma unroll 1
  for (int c = 0; c < 32; ++c) {
    bool f = (te[c] == e);
    unsigned long long m = __ballot(f);
    if (lane == 0) wsum[wv] = __popcll(m);
    __syncthreads();
    int base = run;
    for (int w = 0; w < wv; ++w) base += wsum[w];
    int tot = wsum[0] + wsum[1] + wsum[2] + wsum[3];
    if (f) {
      int i = c * 256 + t;
      int slot = base + __popcll(m & below);
      token_map[slot] = i >> 1;
      gate_w[slot] = tw[c];
      slot_of[i] = slot;
    }
    run += tot;
    __syncthreads();
  }
}

// ---------------- GEMM1: H = gate * silu(X@W1) * (X@W3), grouped, XCD-swizzled ----------------
__global__ __launch_bounds__(256, 2)
void k_gemm1(const unsigned short* __restrict__ Xb, const unsigned short* __restrict__ W1T,
             const unsigned short* __restrict__ W3T, const int* __restrict__ token_map,
             const float* __restrict__ gate_w, const int* __restrict__ ntiles,
             const int* __restrict__ tile_e, const int* __restrict__ tile_m0,
             const int* __restrict__ offsets, const int* __restrict__ counts,
             unsigned short* __restrict__ H) {
  // 480 blocks = 80 m-tiles x 6 n-blocks; group 4 consecutive m-tiles (usually same
  // expert => same W slice) onto the same XCD class (idx % 8).
  int idx = blockIdx.x;
  int xcd = idx & 7, r = idx >> 3;
  int g = (r >> 2) * 8 + xcd;       // 0..119
  int mm = r & 3;
  int ty = (g / 6) * 4 + mm;        // 0..79
  if (ty >= *ntiles) return;
  int n0 = (g % 6) * 128;
  int e = tile_e[ty], m0 = tile_m0[ty];
  int base_slot = offsets[e] + m0;
  int cnt = counts[e] - m0; if (cnt > 128) cnt = 128;

  __shared__ unsigned short As[128 * 32];
  __shared__ unsigned short B1s[128 * 32];
  __shared__ unsigned short B3s[128 * 32];

  int t = threadIdx.x;
  int row = t >> 2, kc = (t & 3) * 8;
  int r0i = base_slot + row;      if (r0i > NSLOT - 1) r0i = NSLOT - 1;
  int r1i = base_slot + 64 + row; if (r1i > NSLOT - 1) r1i = NSLOT - 1;
  const unsigned short* ag0 = Xb + (size_t)token_map[r0i] * DDIM + kc;
  const unsigned short* ag1 = Xb + (size_t)token_map[r1i] * DDIM + kc;
  const unsigned short* b1g0 = W1T + ((size_t)e * NPAD1 + n0 + row) * DDIM + kc;
  const unsigned short* b1g1 = b1g0 + (size_t)64 * DDIM;
  const unsigned short* b3g0 = W3T + ((size_t)e * NPAD1 + n0 + row) * DDIM + kc;
  const unsigned short* b3g1 = b3g0 + (size_t)64 * DDIM;
  unsigned short* asd0 = As + t * 8;   unsigned short* asd1 = As + 2048 + t * 8;
  unsigned short* b1d0 = B1s + t * 8;  unsigned short* b1d1 = B1s + 2048 + t * 8;
  unsigned short* b3d0 = B3s + t * 8;  unsigned short* b3d1 = B3s + 2048 + t * 8;

  int lane = t & 63, wv = t >> 6;
  int wm = (wv >> 1) * 64, wn = (wv & 1) * 64;
  int lm = lane & 15, kg = lane >> 4;
  int ao[4], bo[4];
#pragma unroll
  for (int i = 0; i < 4; ++i) {
    ao[i] = (wm + i * 16 + lm) * 32 + kg * 8;
    bo[i] = (wn + i * 16 + lm) * 32 + kg * 8;
  }

  f32x4 acc1[4][4], acc3[4][4];
#pragma unroll
  for (int i = 0; i < 4; ++i)
#pragma unroll
    for (int j = 0; j < 4; ++j) { acc1[i][j] = 0.f; acc3[i][j] = 0.f; }

  for (int k0 = 0; k0 < DDIM; k0 += 32) {
    __syncthreads();
    gload_lds16(ag0 + k0, asd0);
    gload_lds16(ag1 + k0, asd1);
    gload_lds16(b1g0 + k0, b1d0);
    gload_lds16(b1g1 + k0, b1d1);
    gload_lds16(b3g0 + k0, b3d0);
    gload_lds16(b3g1 + k0, b3d1);
    __syncthreads();
    bf16x8 av[4], b1v[4], b3v[4];
#pragma unroll
    for (int i = 0; i < 4; ++i) {
      av[i]  = *(const bf16x8*)(As + ao[i]);
      b1v[i] = *(const bf16x8*)(B1s + bo[i]);
      b3v[i] = *(const bf16x8*)(B3s + bo[i]);
    }
#pragma unroll
    for (int mi = 0; mi < 4; ++mi)
#pragma unroll
      for (int ni = 0; ni < 4; ++ni) {
        acc1[mi][ni] = __builtin_amdgcn_mfma_f32_16x16x32_bf16(av[mi], b1v[ni], acc1[mi][ni], 0, 0, 0);
        acc3[mi][ni] = __builtin_amdgcn_mfma_f32_16x16x32_bf16(av[mi], b3v[ni], acc3[mi][ni], 0, 0, 0);
      }
  }

  // epilogue: SwiGLU * gate -> bf16 H
#pragma unroll
  for (int mi = 0; mi < 4; ++mi)
#pragma unroll
    for (int rr = 0; rr < 4; ++rr) {
      int orow = wm + mi * 16 + kg * 4 + rr;
      if (orow < cnt) {
        int slot = base_slot + orow;
        float gw = gate_w[slot];
        unsigned short* hrow = H + (size_t)slot * IDIM;
#pragma unroll
        for (int ni = 0; ni < 4; ++ni) {
          int nn = n0 + wn + ni * 16 + lm;
          if (nn < IDIM) {
            float v1 = acc1[mi][ni][rr];
            float v3 = acc3[mi][ni][rr];
            float h = v1 / (1.f + __expf(-v1)) * v3 * gw;
            hrow[nn] = f2bf(h);
          }
        }
      }
    }
}

// ---------------- GEMM2: O2 = H @ W2, grouped, XCD-swizzled ----------------
__global__ __launch_bounds__(256, 3)
void k_gemm2(const unsigned short* __restrict__ H, const unsigned short* __restrict__ W2T,
             const int* __restrict__ ntiles, const int* __restrict__ tile_e,
             const int* __restrict__ tile_m0, const int* __restrict__ offsets,
             const int* __restrict__ counts, float* __restrict__ O2) {
  // 640 blocks = 80 m-tiles x 8 n-blocks.
  int idx = blockIdx.x;
  int xcd = idx & 7, r = idx >> 3;
  int g = (r >> 2) * 8 + xcd;       // 0..159
  int mm = r & 3;
  int ty = (g >> 3) * 4 + mm;       // 0..79
  if (ty >= *ntiles) return;
  int n0 = (g & 7) * 128;
  int e = tile_e[ty], m0 = tile_m0[ty];
  int base_slot = offsets[e] + m0;
  int cnt = counts[e] - m0; if (cnt > 128) cnt = 128;

  __shared__ unsigned short As[128 * 32];
  __shared__ unsigned short Bs[128 * 32];

  int t = threadIdx.x;
  int row = t >> 2, kc = (t & 3) * 8;
  int r0i = base_slot + row;      if (r0i > NSLOT - 1) r0i = NSLOT - 1;
  int r1i = base_slot + 64 + row; if (r1i > NSLOT - 1) r1i = NSLOT - 1;
  const unsigned short* ag0 = H + (size_t)r0i * IDIM + kc;
  const unsigned short* ag1 = H + (size_t)r1i * IDIM + kc;
  const unsigned short* bg0 = W2T + ((size_t)e * DDIM + n0 + row) * IDIM + kc;
  const unsigned short* bg1 = bg0 + (size_t)64 * IDIM;
  unsigned short* asd0 = As + t * 8;  unsigned short* asd1 = As + 2048 + t * 8;
  unsigned short* bd0 = Bs + t * 8;   unsigned short* bd1 = Bs + 2048 + t * 8;

  int lane = t & 63, wv = t >> 6;
  int wm = (wv >> 1) * 64, wn = (wv & 1) * 64;
  int lm = lane & 15, kg = lane >> 4;
  int ao[4], bo[4];
#pragma unroll
  for (int i = 0; i < 4; ++i) {
    ao[i] = (wm + i * 16 + lm) * 32 + kg * 8;
    bo[i] = (wn + i * 16 + lm) * 32 + kg * 8;
  }

  f32x4 acc[4][4];
#pragma unroll
  for (int i = 0; i < 4; ++i)
#pragma unroll
    for (int j = 0; j < 4; ++j) acc[i][j] = 0.f;

  for (int k0 = 0; k0 < IDIM; k0 += 32) {
    __syncthreads();
    gload_lds16(ag0 + k0, asd0);
    gload_lds16(ag1 + k0, asd1);
    gload_lds16(bg0 + k0, bd0);
    gload_lds16(bg1 + k0, bd1);
    __syncthreads();
    bf16x8 av[4], bv[4];
#pragma unroll
    for (int i = 0; i < 4; ++i) {
      av[i] = *(const bf16x8*)(As + ao[i]);
      bv[i] = *(const bf16x8*)(Bs + bo[i]);
    }
#pragma unroll
    for (int mi = 0; mi < 4; ++mi)
#pragma unroll
      for (int ni = 0; ni < 4; ++ni)
        acc[mi][ni] = __builtin_amdgcn_mfma_f32_16x16x32_bf16(av[mi], bv[ni], acc[mi][ni], 0, 0, 0);
  }

#pragma unroll
  for (int mi = 0; mi < 4; ++mi)
#pragma unroll
    for (int rr = 0; rr < 4; ++rr) {
      int orow = wm + mi * 16 + kg * 4 + rr;
      if (orow < cnt) {
        float* op = O2 + (size_t)(base_slot + orow) * DDIM + n0;
#pragma unroll
        for (int ni = 0; ni < 4; ++ni)
          op[wn + ni * 16 + lm] = acc[mi][ni][rr];
      }
    }
}

// ---------------- combine: out[t] = O2[slot0] + O2[slot1] ----------------
__global__ void k_combine(const float* __restrict__ O2, const int* __restrict__ slot_of,
                          float* __restrict__ out) {
  int tk = blockIdx.x, tt = threadIdx.x;
  int s0 = slot_of[2 * tk], s1 = slot_of[2 * tk + 1];
  f32x4 a = ((const f32x4*)(O2 + (size_t)s0 * DDIM))[tt];
  f32x4 b = ((const f32x4*)(O2 + (size_t)s1 * DDIM))[tt];
  ((f32x4*)(out + (size_t)tk * DDIM))[tt] = a + b;
}

extern "C" void kernel_launch(void* const* d_in, const int* in_sizes, int n_in,
                              void* d_out, int out_size, void* d_ws, size_t ws_size,
                              hipStream_t stream) {
  const float* x  = (const float*)d_in[0];
  const float* Wg = (const float*)d_in[1];
  const float* W1 = (const float*)d_in[2];
  const float* W2 = (const float*)d_in[3];   // dict order: x, Wg, W1, W2, W3
  const float* W3 = (const float*)d_in[4];
  float* out = (float*)d_out;

  char* ws = (char*)d_ws;
  size_t off = 0;
  unsigned short* Xb = (unsigned short*)(ws + off); off += (size_t)NTOK * DDIM * 2;
  unsigned short* H  = (unsigned short*)(ws + off); off += (size_t)NSLOT * IDIM * 2;
  float* O2 = (float*)(ws + off); off += (size_t)NSLOT * DDIM * 4;
  unsigned short* W1T = (unsigned short*)(ws + off); off += (size_t)NEXP * NPAD1 * DDIM * 2;
  unsigned short* W3T = (unsigned short*)(ws + off); off += (size_t)NEXP * NPAD1 * DDIM * 2;
  unsigned short* W2T = (unsigned short*)(ws + off); off += (size_t)NEXP * DDIM * IDIM * 2;
  int* counts  = (int*)(ws + off); off += 64;
  int* offsets = (int*)(ws + off); off += 128;
  int* ntiles  = (int*)(ws + off); off += 64;
  int* tile_e  = (int*)(ws + off); off += MAXT * 4;
  int* tile_m0 = (int*)(ws + off); off += MAXT * 4;
  int* tok_e   = (int*)(ws + off); off += NSLOT * 4;
  float* tok_w = (float*)(ws + off); off += NSLOT * 4;
  int* token_map = (int*)(ws + off); off += NSLOT * 4;
  float* gate_w  = (float*)(ws + off); off += NSLOT * 4;
  int* slot_of   = (int*)(ws + off); off += NSLOT * 4;

  k_router<<<1024, 256, 0, stream>>>(x, Wg, tok_e, tok_w, Xb);
  k_count_scan<<<1, 256, 0, stream>>>(tok_e, counts, offsets, ntiles, tile_e, tile_m0);
  k_scatter2<<<NEXP, 256, 0, stream>>>(tok_e, tok_w, offsets, token_map, gate_w, slot_of);
  k_wtrans<<<dim3(16, 12, NEXP), 256, 0, stream>>>(W1, W1T, DDIM, IDIM, NPAD1);
  k_wtrans<<<dim3(16, 12, NEXP), 256, 0, stream>>>(W3, W3T, DDIM, IDIM, NPAD1);
  k_gemm1<<<480, 256, 0, stream>>>(Xb, W1T, W3T, token_map, gate_w, ntiles, tile_e,
                                   tile_m0, offsets, counts, H);
  k_wtrans<<<dim3(11, 16, NEXP), 256, 0, stream>>>(W2, W2T, IDIM, DDIM, DDIM);
  k_gemm2<<<640, 256, 0, stream>>>(H, W2T, ntiles, tile_e, tile_m0, offsets, counts, O2);
  k_combine<<<4096, 256, 0, stream>>>(O2, slot_of, out);
}